// Round 18
// baseline (511.616 us; speedup 1.0000x reference)
//
#include <hip/hip_runtime.h>
#include <math.h>

// R18 = R17's producer/consumer topology + (a) 16 waves for 4/SIMD interleave,
// (b) PERSISTENT blocks: grid 256, each block pipelines 4 samples (32 chunks)
// with no drain between samples.
//   waves 0..11 : FIR, CPW=7 (12x7=84 >= 81). Padded xs -> pure ds_read+fma.
//                 Same codegen family proven at CPW=6/9/11/14; 448-FMA body.
//   waves 12..15: consumers. Stage global chunk g+1 (pf[5] load -> ds_write,
//                 regs die before scan) -> scan global chunk g-1 from
//                 ybuf[(g-1)&1]; scan state resets at sample boundaries;
//                 FC for sample ns fires one phase after its last scan.
// Global chunk g in [0,32): sample ns = g>>3, local chunk cs = g&7.
// LDS = xs[2][147*64] 75264 + ybuf[2][81*65] 42120 + wsh + feat ~115.2 KB
// -> 1 block/CU, 16 waves = 4/SIMD (VGPR~52 <= 64: no cap issue).

#define NTH      1024
#define NFIR     768       // 12 FIR waves
#define CPW      7
#define TC       64
#define XROWS    147       // max padded row read = 83 + 63 = 146
#define YSTRIDE  65
#define T_LEN    500
#define C_OUT    81
#define SPB      4         // samples per block
#define NG       32        // 4 samples x 8 chunks

__global__ __launch_bounds__(NTH)
void snn_ps7_kernel(const float* __restrict__ x,
                    const float* __restrict__ conv_w,
                    const float* __restrict__ conv_b,
                    const float* __restrict__ bn_gamma,
                    const float* __restrict__ bn_beta,
                    const float* __restrict__ bn_mean,
                    const float* __restrict__ bn_var,
                    const float* __restrict__ plif_w,
                    const float* __restrict__ fc_w,
                    const float* __restrict__ fc_b,
                    float* __restrict__ out)
{
    __shared__ float xs[2][XROWS * TC];        // 2 x 37632 B
    __shared__ float ybuf[2][C_OUT * YSTRIDE]; // 2 x 21060 B
    __shared__ float wsh[64];
    __shared__ float feat[C_OUT];              // total ~115.2 KiB

    const int tid    = threadIdx.x;
    const int n_base = blockIdx.x * SPB;
    const int lane   = tid & 63;

    if (tid < 64) wsh[tid] = conv_w[tid];

    // ---- zero FIR pad rows of BOTH xs buffers (written once) ----
    for (int i = tid; i < 32 * TC; i += NTH) { xs[0][i] = 0.0f; xs[1][i] = 0.0f; }
    for (int i = tid; i < (XROWS - 112) * TC; i += NTH) {
        xs[0][112 * TC + i] = 0.0f; xs[1][112 * TC + i] = 0.0f;
    }
    // ---- stage global chunk 0 -> xs[0] rows 32..111 ----
    {
        const float* xn0 = x + (size_t)n_base * (80 * T_LEN);
        for (int i = tid; i < 1280; i += NTH) {
            const int cr = i >> 4, t4 = i & 15;
            float4 v4 = *reinterpret_cast<const float4*>(xn0 + cr * T_LEN + t4 * 4);
            *reinterpret_cast<float4*>(&xs[0][(cr + 32) * TC + t4 * 4]) = v4;
        }
    }

    // ---- consumer per-lane state (tid 768..1023; channel = sid) ----
    const int sid = tid - NFIR;                // <0 for FIR threads
    float v = 0.0f, cnt = 0.0f, inv_c = 0.0f, bb_c = 0.0f, decay = 0.0f;
    if (tid >= NFIR) {
        decay = 1.0f / (1.0f + expf(-plif_w[0]));
        const int ch = (sid >= 0 && sid < C_OUT) ? sid : 0;
        inv_c = bn_gamma[ch] * rsqrtf(bn_var[ch] + 1e-5f);
        bb_c  = conv_b[0] * inv_c + bn_beta[ch] - bn_mean[ch] * inv_c;
    }
    __syncthreads();

    for (int g = 0; g < NG; ++g) {
        const int b = g & 1;

        if (tid < NFIR) {
            // ========== FIR producers (waves 0..11): 7 channels each =======
            const int co0 = (tid >> 6) * CPW;  // 0,7,...,77
            const float* xsb = xs[b];
            float acc[CPW];
            float win[CPW];                    // win[(k+r)%CPW] = padded row co0+k+r
            #pragma unroll
            for (int r = 0; r < CPW; ++r) acc[r] = 0.0f;
            const int base = co0 * TC + lane;
            #pragma unroll
            for (int m = 0; m < CPW - 1; ++m) win[m] = xsb[base + m * TC];
            #pragma unroll
            for (int k = 0; k < 64; ++k) {
                win[(k + CPW - 1) % CPW] = xsb[base + (k + CPW - 1) * TC];
                const float wk = wsh[k];       // LDS broadcast
                #pragma unroll
                for (int r = 0; r < CPW; ++r)
                    acc[r] = fmaf(wk, win[(k + r) % CPW], acc[r]);
            }
            #pragma unroll
            for (int r = 0; r < CPW; ++r) {
                const int co = co0 + r;
                if (co < C_OUT) ybuf[b][co * YSTRIDE + lane] = acc[r];
            }
        } else {
            // ========= consumers (waves 12..15): stage -> scan -> FC =======
            // 1) stage global chunk g+1 -> xs[b^1] (pf regs die here)
            if (g < NG - 1) {
                const int gn  = g + 1;
                const float* xnn = x + (size_t)(n_base + (gn >> 3)) * (80 * T_LEN);
                const int t0n = (gn & 7) * TC;
                float4 pf[5];
                #pragma unroll
                for (int s = 0; s < 5; ++s) {
                    const int i  = s * 256 + sid;   // 1280 items / 256 threads
                    const int cr = i >> 4, t4 = i & 15;
                    int toff = t0n + t4 * 4;
                    if (toff > 496) toff = 496;     // float4: max start = 500-4
                    pf[s] = *reinterpret_cast<const float4*>(xnn + cr * T_LEN + toff);
                }
                #pragma unroll
                for (int s = 0; s < 5; ++s) {
                    const int i  = s * 256 + sid;
                    const int cr = i >> 4, t4 = i & 15;
                    *reinterpret_cast<float4*>(&xs[b ^ 1][(cr + 32) * TC + t4 * 4]) = pf[s];
                }
            }

            // 2) scan global chunk g-1 (sample gs>>3, local cs = gs&7)
            if (g > 0 && sid < C_OUT) {
                const int gs = g - 1;
                const int cs = gs & 7;
                if (cs == 0) { v = 0.0f; cnt = 0.0f; }       // new sample
                const int tcols = (cs == 7) ? 52 : 64;
                const float* yrow = &ybuf[b ^ 1][sid * YSTRIDE];
                #pragma unroll 4
                for (int t = 0; t < tcols; ++t) {
                    const float xt = fmaf(yrow[t], inv_c, bb_c);   // BN
                    v = fmaf(xt - v, decay, v);                    // v += (x-v)*decay
                    const bool s = (v >= 1.0f);
                    cnt += s ? 1.0f : 0.0f;
                    v = s ? 0.0f : v;
                }
                if (cs == 7) feat[sid] = cnt * (1.0f / 500.0f);
            }

            // 3) FC for sample ns = (g>>3)-1, one phase after its last scan
            if ((g & 7) == 1 && g >= 9 && sid < 3) {
                const int ns = (g >> 3) - 1;
                float o = fc_b[sid];
                #pragma unroll 3
                for (int cc = 0; cc < C_OUT; ++cc)
                    o = fmaf(feat[cc], fc_w[sid * C_OUT + cc], o);
                out[(n_base + ns) * 3 + sid] = o;
            }
        }
        __syncthreads();   // single barrier per chunk
    }

    // ---- epilogue: scan chunk (3,7) from ybuf[1], then FC(3) ----
    if (tid >= NFIR && sid < C_OUT) {
        const float* yrow = &ybuf[1][sid * YSTRIDE];
        #pragma unroll 4
        for (int t = 0; t < 52; ++t) {
            const float xt = fmaf(yrow[t], inv_c, bb_c);
            v = fmaf(xt - v, decay, v);
            const bool s = (v >= 1.0f);
            cnt += s ? 1.0f : 0.0f;
            v = s ? 0.0f : v;
        }
        feat[sid] = cnt * (1.0f / 500.0f);
    }
    __syncthreads();

    if (tid < 3) {
        float o = fc_b[tid];
        #pragma unroll 3
        for (int cc = 0; cc < C_OUT; ++cc)
            o = fmaf(feat[cc], fc_w[tid * C_OUT + cc], o);
        out[(n_base + SPB - 1) * 3 + tid] = o;
    }
}

extern "C" void kernel_launch(void* const* d_in, const int* in_sizes, int n_in,
                              void* d_out, int out_size, void* d_ws, size_t ws_size,
                              hipStream_t stream)
{
    const float* x        = (const float*)d_in[0];
    const float* conv_w   = (const float*)d_in[1];
    const float* conv_b   = (const float*)d_in[2];
    const float* bn_gamma = (const float*)d_in[3];
    const float* bn_beta  = (const float*)d_in[4];
    const float* bn_mean  = (const float*)d_in[5];
    const float* bn_var   = (const float*)d_in[6];
    const float* plif_w   = (const float*)d_in[7];
    const float* fc_w     = (const float*)d_in[8];
    const float* fc_b     = (const float*)d_in[9];
    float* out            = (float*)d_out;

    snn_ps7_kernel<<<256, NTH, 0, stream>>>(
        x, conv_w, conv_b, bn_gamma, bn_beta, bn_mean, bn_var,
        plif_w, fc_w, fc_b, out);
}

// Round 19
// 100.904 us; speedup vs baseline: 5.0703x; 5.0703x over previous
//
#include <hip/hip_runtime.h>
#include <math.h>

// R19 = R17 (112us best: 832 thr = 13 waves, CPW=9, VGPR 52) + PERSISTENCE
// as the ONLY change: grid 256, each block pipelines 4 samples = 32 chunks
// with no inter-sample drain (stage of chunk g+1 crosses sample bounds).
// R18 lesson: 1024-thr blocks collapse the VGPR budget to 64 -> 1.1GB spill;
// NEVER exceed 832 threads in this family.
//   waves 0..8 : FIR, CPW=9 (81 slots exactly). Padded xs -> pure ds_read+fma.
//   waves 9..12: consumers. Stage global chunk g+1 (pf[5] load -> ds_write,
//                regs die before scan) -> scan global chunk g-1 from
//                ybuf[(g-1)&1] (state resets at sample start) -> FC one
//                phase after each sample's feat write.
// LDS = xs[2][144*64] + ybuf[2][81*65] + wsh + feat ~ 116.7 KB -> 1 block/CU.

#define NTH      832
#define NFIR     576       // 9 FIR waves
#define CPW      9
#define TC       64
#define XROWS    144       // max padded row read = 72 + 8 + 63 = 143
#define YSTRIDE  65
#define T_LEN    500
#define C_OUT    81
#define SPB      4         // samples per block
#define NG       32        // SPB * 8 chunks

__global__ __launch_bounds__(NTH)
void snn_ps8_kernel(const float* __restrict__ x,
                    const float* __restrict__ conv_w,
                    const float* __restrict__ conv_b,
                    const float* __restrict__ bn_gamma,
                    const float* __restrict__ bn_beta,
                    const float* __restrict__ bn_mean,
                    const float* __restrict__ bn_var,
                    const float* __restrict__ plif_w,
                    const float* __restrict__ fc_w,
                    const float* __restrict__ fc_b,
                    float* __restrict__ out)
{
    __shared__ float xs[2][XROWS * TC];        // 2 x 36864 B
    __shared__ float ybuf[2][C_OUT * YSTRIDE]; // 2 x 21060 B
    __shared__ float wsh[64];
    __shared__ float feat[C_OUT];              // total ~116.7 KiB

    const int tid    = threadIdx.x;
    const int n_base = blockIdx.x * SPB;
    const int lane   = tid & 63;

    if (tid < 64) wsh[tid] = conv_w[tid];

    // ---- zero FIR pad rows of BOTH xs buffers (written once) ----
    for (int i = tid; i < 32 * TC; i += NTH) {
        xs[0][i] = 0.0f;             xs[1][i] = 0.0f;              // rows 0..31
        xs[0][112 * TC + i] = 0.0f;  xs[1][112 * TC + i] = 0.0f;   // rows 112..143
    }
    // ---- stage global chunk 0 -> xs[0] rows 32..111 ----
    {
        const float* xn0 = x + (size_t)n_base * (80 * T_LEN);
        for (int i = tid; i < 1280; i += NTH) {
            const int cr = i >> 4, t4 = i & 15;
            float4 v4 = *reinterpret_cast<const float4*>(xn0 + cr * T_LEN + t4 * 4);
            *reinterpret_cast<float4*>(&xs[0][(cr + 32) * TC + t4 * 4]) = v4;
        }
    }

    // ---- consumer per-lane state (tid 576..831; channel = sid) ----
    const int sid = tid - NFIR;                // <0 for FIR threads
    float v = 0.0f, cnt = 0.0f, inv_c = 0.0f, bb_c = 0.0f, decay = 0.0f;
    if (tid >= NFIR) {
        decay = 1.0f / (1.0f + expf(-plif_w[0]));
        const int ch = (sid < C_OUT) ? sid : 0;
        inv_c = bn_gamma[ch] * rsqrtf(bn_var[ch] + 1e-5f);
        bb_c  = conv_b[0] * inv_c + bn_beta[ch] - bn_mean[ch] * inv_c;
    }
    __syncthreads();

    for (int g = 0; g < NG; ++g) {
        const int b = g & 1;

        if (tid < NFIR) {
            // ========== FIR producers (waves 0..8): 9 channels each ========
            const int co0 = (tid >> 6) * CPW;  // 0,9,...,72
            const float* xsb = xs[b];
            float acc[CPW];
            float win[CPW];                    // win[(k+r)%CPW] = padded row co0+k+r
            #pragma unroll
            for (int r = 0; r < CPW; ++r) acc[r] = 0.0f;
            const int base = co0 * TC + lane;
            #pragma unroll
            for (int m = 0; m < CPW - 1; ++m) win[m] = xsb[base + m * TC];
            #pragma unroll
            for (int k = 0; k < 64; ++k) {
                win[(k + CPW - 1) % CPW] = xsb[base + (k + CPW - 1) * TC];
                const float wk = wsh[k];       // LDS broadcast
                #pragma unroll
                for (int r = 0; r < CPW; ++r)
                    acc[r] = fmaf(wk, win[(k + r) % CPW], acc[r]);
            }
            #pragma unroll
            for (int r = 0; r < CPW; ++r) {
                const int co = co0 + r;
                if (co < C_OUT) ybuf[b][co * YSTRIDE + lane] = acc[r];
            }
        } else {
            // ===== consumers (waves 9..12): stage -> scan -> FC ======
            // 1) stage global chunk g+1 -> xs[b^1] (pf regs die here)
            if (g < NG - 1) {
                const int gn = g + 1;
                const float* xnn = x + (size_t)(n_base + (gn >> 3)) * (80 * T_LEN);
                const int t0n = (gn & 7) * TC;
                float4 pf[5];
                #pragma unroll
                for (int s = 0; s < 5; ++s) {
                    const int i  = s * 256 + sid;   // 1280 items / 256 threads
                    const int cr = i >> 4, t4 = i & 15;
                    int toff = t0n + t4 * 4;
                    if (toff > 496) toff = 496;     // float4: max start = 500-4
                    pf[s] = *reinterpret_cast<const float4*>(xnn + cr * T_LEN + toff);
                }
                #pragma unroll
                for (int s = 0; s < 5; ++s) {
                    const int i  = s * 256 + sid;
                    const int cr = i >> 4, t4 = i & 15;
                    *reinterpret_cast<float4*>(&xs[b ^ 1][(cr + 32) * TC + t4 * 4]) = pf[s];
                }
            }

            // 2) scan global chunk g-1 (sample gs>>3, local chunk cs=gs&7)
            if (g > 0 && sid < C_OUT) {
                const int gs = g - 1;
                const int cs = gs & 7;
                if (cs == 0) { v = 0.0f; cnt = 0.0f; }       // new sample
                const int tcols = (cs == 7) ? 52 : 64;
                const float* yrow = &ybuf[b ^ 1][sid * YSTRIDE];
                #pragma unroll 4
                for (int t = 0; t < tcols; ++t) {
                    const float xt = fmaf(yrow[t], inv_c, bb_c);   // BN
                    v = fmaf(xt - v, decay, v);                    // v += (x-v)*decay
                    const bool s = (v >= 1.0f);
                    cnt += s ? 1.0f : 0.0f;
                    v = s ? 0.0f : v;
                }
                if (cs == 7) feat[sid] = cnt * (1.0f / 500.0f);
            }

            // 3) FC for sample ns=(g>>3)-1 (one barrier after its feat write)
            if ((g & 7) == 1 && g >= 9 && sid < 3) {
                const int ns = (g >> 3) - 1;
                float o = fc_b[sid];
                #pragma unroll 3
                for (int cc = 0; cc < C_OUT; ++cc)
                    o = fmaf(feat[cc], fc_w[sid * C_OUT + cc], o);
                out[(n_base + ns) * 3 + sid] = o;
            }
        }
        __syncthreads();   // single barrier per chunk
    }

    // ---- epilogue: scan last chunk (sample 3, cs=7, 52 cols) from ybuf[1] ----
    if (tid >= NFIR && sid < C_OUT) {
        const float* yrow = &ybuf[1][sid * YSTRIDE];
        #pragma unroll 4
        for (int t = 0; t < 52; ++t) {
            const float xt = fmaf(yrow[t], inv_c, bb_c);
            v = fmaf(xt - v, decay, v);
            const bool s = (v >= 1.0f);
            cnt += s ? 1.0f : 0.0f;
            v = s ? 0.0f : v;
        }
        feat[sid] = cnt * (1.0f / 500.0f);
    }
    __syncthreads();

    if (tid < 3) {
        float o = fc_b[tid];
        #pragma unroll 3
        for (int cc = 0; cc < C_OUT; ++cc)
            o = fmaf(feat[cc], fc_w[tid * C_OUT + cc], o);
        out[(n_base + SPB - 1) * 3 + tid] = o;
    }
}

extern "C" void kernel_launch(void* const* d_in, const int* in_sizes, int n_in,
                              void* d_out, int out_size, void* d_ws, size_t ws_size,
                              hipStream_t stream)
{
    const float* x        = (const float*)d_in[0];
    const float* conv_w   = (const float*)d_in[1];
    const float* conv_b   = (const float*)d_in[2];
    const float* bn_gamma = (const float*)d_in[3];
    const float* bn_beta  = (const float*)d_in[4];
    const float* bn_mean  = (const float*)d_in[5];
    const float* bn_var   = (const float*)d_in[6];
    const float* plif_w   = (const float*)d_in[7];
    const float* fc_w     = (const float*)d_in[8];
    const float* fc_b     = (const float*)d_in[9];
    float* out            = (float*)d_out;

    snn_ps8_kernel<<<256, NTH, 0, stream>>>(
        x, conv_w, conv_b, bn_gamma, bn_beta, bn_mean, bn_var,
        plif_w, fc_w, fc_b, out);
}